// Round 5
// baseline (88.362 us; speedup 1.0000x reference)
//
#include <hip/hip_runtime.h>
#include <hip/hip_bf16.h>
#include <cstdint>

// Problem constants (from reference): L=12, B=8192, D=1024, K=64
#define NL 12
#define NB 8192
#define ND 1024
#define NK 64
#define TB 16   // b-rows per block

typedef __attribute__((ext_vector_type(8))) short bf16x8;
typedef __attribute__((ext_vector_type(4))) float f32x4;

__device__ __forceinline__ unsigned short f2bf(float f) {
  union { float f; unsigned int u; } v; v.f = f;
  unsigned int u = v.u;
  u += 0x7FFFu + ((u >> 16) & 1u);   // round-to-nearest-even
  return (unsigned short)(u >> 16);
}

// ------------------------------------------------- fused mean+GEMM+tanh
// Single kernel. W is converted to per-wave VGPR bf16 fragments in a
// preamble (64 VGPRs/lane); phase 2 is pure LDS + MFMA. NT loads on x
// (proven +12% in R4 A/B). Phase 1 uses strict 6+6 load batches to keep
// peak VGPR under the 128 cap from __launch_bounds__(512,4).
__global__ void __launch_bounds__(512, 4)
fused_mean_gemm_tanh(const float* __restrict__ x,
                     const float* __restrict__ W,
                     const float* __restrict__ bias, float* __restrict__ out) {
  // xm tile: [TB][1024] bf16, row stride 2048 B, XOR-swizzled (T2)
  __shared__ __align__(16) unsigned char xs[TB * 2048];   // 32 KB
  __shared__ f32x4 pred[4 * 64];                          // 4 KB partials

  const int tid = threadIdx.x;
  const int b0 = blockIdx.x * TB;

  const int lane  = tid & 63;
  const int w     = tid >> 6;     // wave id
  const int ktile = w & 3;        // k-tile (16 outputs)
  const int khalf = w >> 2;       // K-dim half (cols 0-511 / 512-1023)
  const int mn    = lane & 15;    // A: b-row | B: W-row (k) | D: col (k)
  const int g     = lane >> 4;    // k-group within fragment
  const int kn0   = ktile * 16;

  // ---- W preamble: fp32 -> per-wave bf16 MFMA fragments, kept in VGPRs ----
  bf16x8 wfrag[16];
  {
    const float* Wrow = W + (size_t)(kn0 + mn) * ND + khalf * 512;
#pragma unroll
    for (int ss = 0; ss < 16; ++ss) {
      const float* wp = Wrow + 32 * ss + 8 * g;   // 8 consecutive fp32
      float4 w0 = *(const float4*)(wp);
      float4 w1 = *(const float4*)(wp + 4);
      bf16x8 f;
      f[0] = (short)f2bf(w0.x); f[1] = (short)f2bf(w0.y);
      f[2] = (short)f2bf(w0.z); f[3] = (short)f2bf(w0.w);
      f[4] = (short)f2bf(w1.x); f[5] = (short)f2bf(w1.y);
      f[6] = (short)f2bf(w1.z); f[7] = (short)f2bf(w1.w);
      wfrag[ss] = f;
    }
  }

  // -------- Phase 1: xm = sum_l x[l, b0+i, :]  (HBM-bound, NT loads) ------
  // 512 threads cover 2 rows per sweep; 8 sweeps. 6+6 layer batches.
  const int rhalf = tid >> 8;        // 0/1 -> which row of the pair
  const int t     = tid & 255;       // float4 index within the row
  const f32x4* x4 = (const f32x4*)x;
  const size_t ls = (size_t)NB * (ND / 4);   // layer stride in float4s

  for (int s = 0; s < 8; ++s) {
    const int i = 2 * s + rhalf;
    const f32x4* p = x4 + (size_t)(b0 + i) * (ND / 4) + t;
    // batch A: layers 0-5
    f32x4 v0 = __builtin_nontemporal_load(p);
    f32x4 v1 = __builtin_nontemporal_load(p + 1 * ls);
    f32x4 v2 = __builtin_nontemporal_load(p + 2 * ls);
    f32x4 v3 = __builtin_nontemporal_load(p + 3 * ls);
    f32x4 v4 = __builtin_nontemporal_load(p + 4 * ls);
    f32x4 v5 = __builtin_nontemporal_load(p + 5 * ls);
    f32x4 a = ((v0 + v1) + (v2 + v3)) + (v4 + v5);
    // batch B: layers 6-11
    v0 = __builtin_nontemporal_load(p + 6 * ls);
    v1 = __builtin_nontemporal_load(p + 7 * ls);
    v2 = __builtin_nontemporal_load(p + 8 * ls);
    v3 = __builtin_nontemporal_load(p + 9 * ls);
    v4 = __builtin_nontemporal_load(p + 10 * ls);
    v5 = __builtin_nontemporal_load(p + 11 * ls);
    a += ((v0 + v1) + (v2 + v3)) + (v4 + v5);

    unsigned int lo = (unsigned)f2bf(a[0]) | ((unsigned)f2bf(a[1]) << 16);
    unsigned int hi = (unsigned)f2bf(a[2]) | ((unsigned)f2bf(a[3]) << 16);
    int byte = i * 2048 + t * 8;
    byte ^= (i & 7) << 4;            // T2 XOR swizzle
    uint2 u; u.x = lo; u.y = hi;
    *(uint2*)(xs + byte) = u;
  }
  __syncthreads();

  // -------- Phase 2: out[b0+m][k] = tanh(dot/12 + bias), pure LDS+MFMA ----
  f32x4 acc = {0.f, 0.f, 0.f, 0.f};
  const int abase = mn * 2048 + 16 * g;
  const int axor  = (mn & 7) << 4;

#pragma unroll
  for (int ss = 0; ss < 16; ++ss) {
    const int step = khalf * 16 + ss;
    int byte = (abase + 64 * step) ^ axor;
    bf16x8 afrag = *(const bf16x8*)(xs + byte);        // ds_read_b128
    acc = __builtin_amdgcn_mfma_f32_16x16x32_bf16(afrag, wfrag[ss], acc, 0, 0, 0);
  }

  if (w >= 4) pred[(w - 4) * 64 + lane] = acc;
  __syncthreads();

  if (w < 4) {
    f32x4 o = pred[w * 64 + lane];
    acc += o;
    // C/D layout (m89-verified): col = lane&15, row = 4*(lane>>4) + reg
    const float bv = bias[kn0 + mn];
#pragma unroll
    for (int r = 0; r < 4; ++r) {
      int row = 4 * g + r;
      float val = tanhf(acc[r] * (1.0f / 12.0f) + bv);
      out[(size_t)(b0 + row) * NK + kn0 + mn] = val;
    }
  }
}

extern "C" void kernel_launch(void* const* d_in, const int* in_sizes, int n_in,
                              void* d_out, int out_size, void* d_ws, size_t ws_size,
                              hipStream_t stream) {
  const float* x    = (const float*)d_in[0];
  const float* W    = (const float*)d_in[1];
  const float* bias = (const float*)d_in[2];
  float* out = (float*)d_out;

  hipLaunchKernelGGL(fused_mean_gemm_tanh, dim3(NB / TB), dim3(512), 0, stream,
                     x, W, bias, out);
}

// Round 6
// 74.694 us; speedup vs baseline: 1.1830x; 1.1830x over previous
//
#include <hip/hip_runtime.h>
#include <hip/hip_bf16.h>
#include <cstdint>

// Problem constants (from reference): L=12, B=8192, D=1024, K=64
#define NL 12
#define NB 8192
#define ND 1024
#define NK 64
#define TB 16   // b-rows per block

typedef __attribute__((ext_vector_type(8))) short bf16x8;
typedef __attribute__((ext_vector_type(4))) float f32x4;

__device__ __forceinline__ unsigned short f2bf(float f) {
  union { float f; unsigned int u; } v; v.f = f;
  unsigned int u = v.u;
  u += 0x7FFFu + ((u >> 16) & 1u);   // round-to-nearest-even
  return (unsigned short)(u >> 16);
}

// ------------------------------------------------- fused mean+GEMM+tanh
// Single kernel. Phase 1 is R2's proven streaming loop (12-batch NT loads,
// 74.05us champion). W fp32->bf16 conversion happens AFTER phase 1 (fence
// prevents hoisting) so wfrag[16] (64 VGPRs) is never live during phase 1
// -> no spill under the 128-VGPR cap (R5's mistake). No wconv kernel.
__global__ void __launch_bounds__(512, 4)
fused_mean_gemm_tanh(const float* __restrict__ x,
                     const float* __restrict__ W,
                     const float* __restrict__ bias, float* __restrict__ out) {
  // xm tile: [TB][1024] bf16, row stride 2048 B, XOR-swizzled (T2)
  __shared__ __align__(16) unsigned char xs[TB * 2048];   // 32 KB
  __shared__ f32x4 pred[4 * 64];                          // 4 KB partials

  const int tid = threadIdx.x;
  const int b0 = blockIdx.x * TB;

  // -------- Phase 1: xm = sum_l x[l, b0+i, :]  (HBM-bound, NT loads) ------
  // 512 threads cover 2 rows per sweep; 8 sweeps.  (identical to R2)
  const int rhalf = tid >> 8;        // 0/1 -> which row of the pair
  const int t     = tid & 255;       // float4 index within the row
  const f32x4* x4 = (const f32x4*)x;

  for (int s = 0; s < 8; ++s) {
    const int i = 2 * s + rhalf;
    const f32x4* p = x4 + (size_t)(b0 + i) * (ND / 4) + t;
    f32x4 a = __builtin_nontemporal_load(p);
#pragma unroll
    for (int l = 1; l < NL; ++l) {
      f32x4 v = __builtin_nontemporal_load(p + (size_t)l * (NB * (ND / 4)));
      a += v;
    }
    unsigned int lo = (unsigned)f2bf(a[0]) | ((unsigned)f2bf(a[1]) << 16);
    unsigned int hi = (unsigned)f2bf(a[2]) | ((unsigned)f2bf(a[3]) << 16);
    int byte = i * 2048 + t * 8;
    byte ^= (i & 7) << 4;            // T2 XOR swizzle
    uint2 u; u.x = lo; u.y = hi;
    *(uint2*)(xs + byte) = u;
  }
  __syncthreads();

  // Fence: keep the W loads BELOW phase 1 so their VGPRs don't extend
  // phase-1 live ranges (R5 post-mortem).
  asm volatile("" ::: "memory");

  // -------- W slice: fp32 -> per-wave bf16 MFMA fragments (L2-resident) ---
  const int lane  = tid & 63;
  const int w     = tid >> 6;     // wave id
  const int ktile = w & 3;        // k-tile (16 outputs)
  const int khalf = w >> 2;       // K-dim half
  const int mn    = lane & 15;    // A: b-row | B: W-row (k) | D: col (k)
  const int g     = lane >> 4;    // k-group within fragment
  const int kn0   = ktile * 16;

  bf16x8 wfrag[16];
  {
    const float* Wrow = W + (size_t)(kn0 + mn) * ND + khalf * 512;
#pragma unroll
    for (int ss = 0; ss < 16; ++ss) {
      const float* wp = Wrow + 32 * ss + 8 * g;   // 8 consecutive fp32
      float4 w0 = *(const float4*)(wp);
      float4 w1 = *(const float4*)(wp + 4);
      bf16x8 f;
      f[0] = (short)f2bf(w0.x); f[1] = (short)f2bf(w0.y);
      f[2] = (short)f2bf(w0.z); f[3] = (short)f2bf(w0.w);
      f[4] = (short)f2bf(w1.x); f[5] = (short)f2bf(w1.y);
      f[6] = (short)f2bf(w1.z); f[7] = (short)f2bf(w1.w);
      wfrag[ss] = f;
    }
  }

  // -------- Phase 2: out[b0+m][k] = tanh(dot/12 + bias), pure LDS+MFMA ----
  f32x4 acc = {0.f, 0.f, 0.f, 0.f};
  const int abase = mn * 2048 + 16 * g;
  const int axor  = (mn & 7) << 4;

#pragma unroll
  for (int ss = 0; ss < 16; ++ss) {
    const int step = khalf * 16 + ss;
    int byte = (abase + 64 * step) ^ axor;
    bf16x8 afrag = *(const bf16x8*)(xs + byte);        // ds_read_b128
    acc = __builtin_amdgcn_mfma_f32_16x16x32_bf16(afrag, wfrag[ss], acc, 0, 0, 0);
  }

  if (w >= 4) pred[(w - 4) * 64 + lane] = acc;
  __syncthreads();

  if (w < 4) {
    f32x4 o = pred[w * 64 + lane];
    acc += o;
    // C/D layout (m89-verified): col = lane&15, row = 4*(lane>>4) + reg
    const float bv = bias[kn0 + mn];
#pragma unroll
    for (int r = 0; r < 4; ++r) {
      int row = 4 * g + r;
      float val = tanhf(acc[r] * (1.0f / 12.0f) + bv);
      out[(size_t)(b0 + row) * NK + kn0 + mn] = val;
    }
  }
}

extern "C" void kernel_launch(void* const* d_in, const int* in_sizes, int n_in,
                              void* d_out, int out_size, void* d_ws, size_t ws_size,
                              hipStream_t stream) {
  const float* x    = (const float*)d_in[0];
  const float* W    = (const float*)d_in[1];
  const float* bias = (const float*)d_in[2];
  float* out = (float*)d_out;

  hipLaunchKernelGGL(fused_mean_gemm_tanh, dim3(NB / TB), dim3(512), 0, stream,
                     x, W, bias, out);
}

// Round 7
// 71.153 us; speedup vs baseline: 1.2419x; 1.0498x over previous
//
#include <hip/hip_runtime.h>
#include <hip/hip_bf16.h>
#include <cstdint>

// Problem constants (from reference): L=12, B=8192, D=1024, K=64
#define NL 12
#define NB 8192
#define ND 1024
#define NK 64
#define TB 16   // b-rows per block

typedef __attribute__((ext_vector_type(8))) short bf16x8;
typedef __attribute__((ext_vector_type(4))) float f32x4;

__device__ __forceinline__ unsigned short f2bf(float f) {
  union { float f; unsigned int u; } v; v.f = f;
  unsigned int u = v.u;
  u += 0x7FFFu + ((u >> 16) & 1u);   // round-to-nearest-even
  return (unsigned short)(u >> 16);
}

// ---------------------------------------------------------------- W -> bf16
__global__ void __launch_bounds__(256)
wconv_kernel(const float* __restrict__ W, uint2* __restrict__ Wb) {
  int i = blockIdx.x * 256 + threadIdx.x;          // 16384 float4s
  f32x4 v = *((const f32x4*)W + i);
  uint2 u;
  u.x = (unsigned)f2bf(v[0]) | ((unsigned)f2bf(v[1]) << 16);
  u.y = (unsigned)f2bf(v[2]) | ((unsigned)f2bf(v[3]) << 16);
  Wb[i] = u;
}

// ------------------------------------------------- fused mean+GEMM+tanh
// R2 structure + tail-hiding: all 16 Wb fragment loads are issued between
// the end of phase 1 and the barrier, so their L2 BW/latency hides under
// the barrier wait instead of being an exposed all-blocks-at-once tail.
// wfrag (64 VGPR) is never live during the 12-deep streaming batches
// (R5 post-mortem), so peak VGPR stays < 128.
__global__ void __launch_bounds__(512, 4)
fused_mean_gemm_tanh(const float* __restrict__ x,
                     const unsigned short* __restrict__ Wb,
                     const float* __restrict__ bias, float* __restrict__ out) {
  // xm tile: [TB][1024] bf16, row stride 2048 B, XOR-swizzled (T2)
  __shared__ __align__(16) unsigned char xs[TB * 2048];   // 32 KB
  __shared__ f32x4 pred[4 * 64];                          // 4 KB partials

  const int tid = threadIdx.x;
  const int b0 = blockIdx.x * TB;

  // -------- Phase 1: xm = sum_l x[l, b0+i, :]  (HBM-bound, NT loads) ------
  // 512 threads cover 2 rows per sweep; 8 sweeps.  (identical to R2)
  const int rhalf = tid >> 8;        // 0/1 -> which row of the pair
  const int t     = tid & 255;       // float4 index within the row
  const f32x4* x4 = (const f32x4*)x;

  for (int s = 0; s < 8; ++s) {
    const int i = 2 * s + rhalf;
    const f32x4* p = x4 + (size_t)(b0 + i) * (ND / 4) + t;
    f32x4 a = __builtin_nontemporal_load(p);
#pragma unroll
    for (int l = 1; l < NL; ++l) {
      f32x4 v = __builtin_nontemporal_load(p + (size_t)l * (NB * (ND / 4)));
      a += v;
    }
    unsigned int lo = (unsigned)f2bf(a[0]) | ((unsigned)f2bf(a[1]) << 16);
    unsigned int hi = (unsigned)f2bf(a[2]) | ((unsigned)f2bf(a[3]) << 16);
    int byte = i * 2048 + t * 8;
    byte ^= (i & 7) << 4;            // T2 XOR swizzle
    uint2 u; u.x = lo; u.y = hi;
    *(uint2*)(xs + byte) = u;
  }

  // -------- Wb prefetch: issue BEFORE the barrier, consume after ----------
  const int lane  = tid & 63;
  const int w     = tid >> 6;     // wave id
  const int ktile = w & 3;        // k-tile (16 outputs)
  const int khalf = w >> 2;       // K-dim half
  const int mn    = lane & 15;    // A: b-row | B: W-row (k) | D: col (k)
  const int g     = lane >> 4;    // k-group within fragment
  const int kn0   = ktile * 16;

  bf16x8 wfrag[16];
  {
    const unsigned short* Wrow = Wb + (size_t)(kn0 + mn) * ND + khalf * 512;
#pragma unroll
    for (int ss = 0; ss < 16; ++ss)
      wfrag[ss] = *(const bf16x8*)(Wrow + 32 * ss + 8 * g);
  }
  const float bv = bias[kn0 + mn];
  __builtin_amdgcn_sched_barrier(0);   // don't sink the prefetch past the barrier
  __syncthreads();

  // -------- Phase 2: out[b0+m][k] = tanh(dot/12 + bias), pure LDS+MFMA ----
  f32x4 acc = {0.f, 0.f, 0.f, 0.f};
  const int abase = mn * 2048 + 16 * g;
  const int axor  = (mn & 7) << 4;

#pragma unroll
  for (int ss = 0; ss < 16; ++ss) {
    const int step = khalf * 16 + ss;
    int byte = (abase + 64 * step) ^ axor;
    bf16x8 afrag = *(const bf16x8*)(xs + byte);        // ds_read_b128
    acc = __builtin_amdgcn_mfma_f32_16x16x32_bf16(afrag, wfrag[ss], acc, 0, 0, 0);
  }

  if (w >= 4) pred[(w - 4) * 64 + lane] = acc;
  __syncthreads();

  if (w < 4) {
    f32x4 o = pred[w * 64 + lane];
    acc += o;
    // C/D layout (m89-verified): col = lane&15, row = 4*(lane>>4) + reg
#pragma unroll
    for (int r = 0; r < 4; ++r) {
      int row = 4 * g + r;
      float val = tanhf(acc[r] * (1.0f / 12.0f) + bv);
      out[(size_t)(b0 + row) * NK + kn0 + mn] = val;
    }
  }
}

extern "C" void kernel_launch(void* const* d_in, const int* in_sizes, int n_in,
                              void* d_out, int out_size, void* d_ws, size_t ws_size,
                              hipStream_t stream) {
  const float* x    = (const float*)d_in[0];
  const float* W    = (const float*)d_in[1];
  const float* bias = (const float*)d_in[2];
  float* out = (float*)d_out;
  unsigned short* Wb = (unsigned short*)d_ws;   // 64*1024 bf16 = 128 KB

  hipLaunchKernelGGL(wconv_kernel, dim3(NK * ND / 4 / 256), dim3(256), 0,
                     stream, W, (uint2*)Wb);
  hipLaunchKernelGGL(fused_mean_gemm_tanh, dim3(NB / TB), dim3(512), 0, stream,
                     x, Wb, bias, out);
}